// Round 2
// baseline (1521.660 us; speedup 1.0000x reference)
//
#include <hip/hip_runtime.h>
#include <math.h>

#define N_CELL 400000
#define N_NET  100000
#define E_PIN  1600000
#define E2     400000

// ---- float <-> order-preserving uint key (for atomicMax on f32) ----
__device__ __forceinline__ unsigned fkey(float f) {
    unsigned u = __float_as_uint(f);
    return (u & 0x80000000u) ? ~u : (u | 0x80000000u);
}
__device__ __forceinline__ float unfkey(unsigned k) {
    unsigned u = (k & 0x80000000u) ? (k & 0x7fffffffu) : ~k;
    return __uint_as_float(u);
}

// ---- Stage A: edge-parallel segment sum/max/count over pins (both dirs) ----
__global__ void __launch_bounds__(256) k_scatter(
    const float* __restrict__ cell_feat, const float* __restrict__ net_feat,
    const int* __restrict__ src, const int* __restrict__ dst,
    float* __restrict__ net_sum, unsigned* __restrict__ net_maxk, float* __restrict__ net_cnt,
    float* __restrict__ cell_sum, unsigned* __restrict__ cell_maxk, float* __restrict__ cell_cnt)
{
    int id = blockIdx.x * 256 + threadIdx.x;
    if (id >= E_PIN * 8) return;
    int e = id >> 3, k = id & 7;
    int s = src[e], d = dst[e];
    float cf = cell_feat[s * 8 + k];
    atomicAdd(&net_sum[d * 8 + k], cf);
    atomicMax(&net_maxk[d * 8 + k], fkey(cf));
    float nf = net_feat[d * 8 + k];
    atomicAdd(&cell_sum[s * 8 + k], nf);
    atomicMax(&cell_maxk[s * 8 + k], fkey(nf));
    if (k == 0) {
        atomicAdd(&net_cnt[d], 1.0f);
        atomicAdd(&cell_cnt[s], 1.0f);
    }
}

// ---- Stage B: node MLP  out = tanh([feat, sum/cnt, max] @ W + b), W: 24x64 ----
__global__ void __launch_bounds__(256) k_node24(
    const float* __restrict__ feat, const float* __restrict__ sum,
    const unsigned* __restrict__ maxk, const float* __restrict__ cnt,
    const float* __restrict__ W, const float* __restrict__ b,
    float* __restrict__ out, int nrows)
{
    __shared__ float Ws[24 * 64];
    __shared__ float bs[64];
    __shared__ float xs[4][24];
    int tid = threadIdx.x;
    for (int i = tid; i < 24 * 64; i += 256) Ws[i] = W[i];
    if (tid < 64) bs[tid] = b[tid];
    int r = tid >> 6, l = tid & 63;
    int row = blockIdx.x * 4 + r;
    if (row < nrows) {
        if (l < 8) {
            xs[r][l] = feat[row * 8 + l];
        } else if (l < 16) {
            float c = fmaxf(cnt[row], 1.0f);
            xs[r][l] = sum[row * 8 + (l - 8)] / c;
        } else if (l < 24) {
            float c = cnt[row];
            xs[r][l] = (c > 0.0f) ? unfkey(maxk[row * 8 + (l - 16)]) : 0.0f;
        }
    }
    __syncthreads();
    if (row < nrows) {
        float acc = bs[l];
        #pragma unroll
        for (int k = 0; k < 24; ++k) acc += xs[r][k] * Ws[k * 64 + l];
        out[row * 64 + l] = tanhf(acc);
    }
}

// ---- hnW = hn @ W_neigh  (64x64), 4 rows per block ----
__global__ void __launch_bounds__(256) k_hnw(
    const float* __restrict__ hn, const float* __restrict__ Wn_g,
    float* __restrict__ hnW, int nrows)
{
    __shared__ float Wn[64 * 64];
    __shared__ float xs[4][64];
    int tid = threadIdx.x;
    for (int i = tid; i < 64 * 64; i += 256) Wn[i] = Wn_g[i];
    int r = tid >> 6, l = tid & 63;
    int row = blockIdx.x * 4 + r;
    if (row < nrows) xs[r][l] = hn[row * 64 + l];
    __syncthreads();
    if (row < nrows) {
        float acc = 0.0f;
        #pragma unroll
        for (int k = 0; k < 64; ++k) acc += xs[r][k] * Wn[k * 64 + l];
        hnW[row * 64 + l] = acc;
    }
}

// ---- hidden init (in-place): hc := hc @ W_self + b_sage ----
__global__ void __launch_bounds__(256) k_self(
    float* __restrict__ hc, const float* __restrict__ Ws_g,
    const float* __restrict__ bsage, int nrows)
{
    __shared__ float Ws[64 * 64];
    __shared__ float bs[64];
    __shared__ float xs[4][64];
    int tid = threadIdx.x;
    for (int i = tid; i < 64 * 64; i += 256) Ws[i] = Ws_g[i];
    if (tid < 64) bs[tid] = bsage[tid];
    int r = tid >> 6, l = tid & 63;
    int row = blockIdx.x * 4 + r;
    if (row < nrows) xs[r][l] = hc[row * 64 + l];
    __syncthreads();
    if (row < nrows) {
        float acc = bs[l];
        #pragma unroll
        for (int k = 0; k < 64; ++k) acc += xs[r][k] * Ws[k * 64 + l];
        hc[row * 64 + l] = acc;   // safe: rows staged in shared by this block only
    }
}

// ---- Stage C: ew[e] = tanh(tanh(p@Wp+bp)@We+be) / max(cnt[src[e]],1) ----
__global__ void __launch_bounds__(256) k_ew(
    const float* __restrict__ pin_feat,
    const float* __restrict__ W_pin, const float* __restrict__ b_pin,
    const float* __restrict__ W_ew, const float* __restrict__ b_ew,
    const int* __restrict__ src, const float* __restrict__ cell_cnt,
    float* __restrict__ ew)
{
    __shared__ float Wp[8 * 16];
    __shared__ float bp[16];
    __shared__ float We[16];
    __shared__ float be_s;
    int tid = threadIdx.x;
    if (tid < 128) Wp[tid] = W_pin[tid];
    if (tid < 16) { bp[tid] = b_pin[tid]; We[tid] = W_ew[tid]; }
    if (tid == 0) be_s = b_ew[0];
    __syncthreads();
    int e = blockIdx.x * 256 + tid;
    if (e >= E_PIN) return;
    float p[8];
    #pragma unroll
    for (int k = 0; k < 8; ++k) p[k] = pin_feat[e * 8 + k];
    float acc = be_s;
    #pragma unroll
    for (int j = 0; j < 16; ++j) {
        float h = bp[j];
        #pragma unroll
        for (int k = 0; k < 8; ++k) h += p[k] * Wp[k * 16 + j];
        acc += tanhf(h) * We[j];
    }
    float c = fmaxf(cell_cnt[src[e]], 1.0f);
    ew[e] = tanhf(acc) / c;
}

// ---- Stage D: hidden[src] += hnW[dst] * ew  (per edge,dim; ew pre-scaled) ----
__global__ void __launch_bounds__(256) k_msg(
    const float* __restrict__ hnW, const float* __restrict__ ew,
    const int* __restrict__ src, const int* __restrict__ dst,
    float* __restrict__ hidden)
{
    int id = blockIdx.x * 256 + threadIdx.x;
    if (id >= E_PIN * 64) return;
    int e = id >> 6, d = id & 63;
    atomicAdd(&hidden[src[e] * 64 + d], hnW[dst[e] * 64 + d] * ew[e]);
}

// ---- Stage E: edge readout, one 64-lane wave per edge ----
__global__ void __launch_bounds__(256) k_edge(
    const float* __restrict__ hidden, const float* __restrict__ hn,
    const int* __restrict__ fa, const int* __restrict__ so, const int* __restrict__ gf,
    const int* __restrict__ fsn, const int* __restrict__ gfn,
    const float* __restrict__ W_dis, const float* __restrict__ b_dis,
    const float* __restrict__ W_def, const float* __restrict__ b_def,
    const float* __restrict__ cell_size, float* __restrict__ out)
{
    int e = blockIdx.x * 4 + (threadIdx.x >> 6);
    int l = threadIdx.x & 63;
    if (e >= E2) return;
    int f = fa[e], s = so[e], g = gf[e], nf = fsn[e], ng = gfn[e];
    float hf = hidden[f * 64 + l];
    float hs = hidden[s * 64 + l];
    float hg = hidden[g * 64 + l];
    float vnf = hn[nf * 64 + l];
    float vng = hn[ng * 64 + l];
    float dis = hf * W_dis[l] + hs * W_dis[64 + l] + vnf * W_dis[128 + l];
    float de  = hg * W_def[l] + hf * W_def[64 + l] + hs * W_def[128 + l]
              + vng * W_def[192 + l] + vnf * W_def[256 + l];
    #pragma unroll
    for (int o = 32; o > 0; o >>= 1) {
        dis += __shfl_down(dis, o);
        de  += __shfl_down(de, o);
    }
    if (l == 0) {
        float d1 = expf(-2.0f + 15.0f * tanhf(dis + b_dis[0]));
        float d2 = tanhf(de + b_def[0]) * 6.28318530717958647692f;
        float bx = (cell_size[f * 2 + 0] + cell_size[s * 2 + 0]) * 0.5f;
        float by = (cell_size[f * 2 + 1] + cell_size[s * 2 + 1]) * 0.5f;
        out[e] = d1 + fminf(bx, by);
        out[E2 + e] = d2;
    }
}

extern "C" void kernel_launch(void* const* d_in, const int* in_sizes, int n_in,
                              void* d_out, int out_size, void* d_ws, size_t ws_size,
                              hipStream_t stream)
{
    const float* cell_feat = (const float*)d_in[0];
    const float* net_feat  = (const float*)d_in[1];
    const float* pin_feat  = (const float*)d_in[2];
    const float* cell_size = (const float*)d_in[3];
    const float* W_cell = (const float*)d_in[4];
    const float* b_cell = (const float*)d_in[5];
    const float* W_net  = (const float*)d_in[6];
    const float* b_net  = (const float*)d_in[7];
    const float* W_pin  = (const float*)d_in[8];
    const float* b_pin  = (const float*)d_in[9];
    const float* W_ew   = (const float*)d_in[10];
    const float* b_ew   = (const float*)d_in[11];
    const float* W_self = (const float*)d_in[12];
    const float* W_neigh= (const float*)d_in[13];
    const float* b_sage = (const float*)d_in[14];
    const float* W_dis  = (const float*)d_in[15];
    const float* b_dis  = (const float*)d_in[16];
    const float* W_def  = (const float*)d_in[17];
    const float* b_def  = (const float*)d_in[18];
    const int* pins_src = (const int*)d_in[19];
    const int* pins_dst = (const int*)d_in[20];
    const int* fathers  = (const int*)d_in[21];
    const int* sons     = (const int*)d_in[22];
    const int* grandf   = (const int*)d_in[23];
    const int* fs_nets  = (const int*)d_in[24];
    const int* gf_nets  = (const int*)d_in[25];

    // ---- compact workspace layout (256B aligned), scratch reuse ----
    char* ws = (char*)d_ws;
    size_t off = 0;
    auto alloc = [&](size_t bytes) -> void* {
        void* p = ws + off;
        off += (bytes + 255) & ~(size_t)255;
        return p;
    };
    // persistent through msg phase:
    float*    cell_cnt  = (float*)   alloc((size_t)N_CELL * 4);           // 1.6MB
    // phase-A scratch block; hnW overlays it after stage B:
    size_t scratch_base = off;
    float*    net_sum   = (float*)   alloc((size_t)N_NET * 8 * 4);        // 3.2MB
    unsigned* net_maxk  = (unsigned*)alloc((size_t)N_NET * 8 * 4);        // 3.2MB
    float*    net_cnt   = (float*)   alloc((size_t)N_NET * 4);            // 0.4MB
    float*    cell_sum  = (float*)   alloc((size_t)N_CELL * 8 * 4);       // 12.8MB
    unsigned* cell_maxk = (unsigned*)alloc((size_t)N_CELL * 8 * 4);       // 12.8MB
    size_t zero_bytes = off;                 // cell_cnt + scratch: zero at start
    float*    hnW       = (float*)(ws + scratch_base);                    // overlay, 25.6MB
    float*    ew  = (float*)alloc((size_t)E_PIN * 4);                     // 6.4MB
    float*    hc  = (float*)alloc((size_t)N_CELL * 64 * 4);               // 102.4MB (becomes hidden)
    float*    hn  = (float*)alloc((size_t)N_NET * 64 * 4);                // 25.6MB
    if (off > ws_size) return;  // workspace too small: fail loudly, don't fault

    hipMemsetAsync(d_ws, 0, zero_bytes, stream);

    // Stage A: segment sum/max/count both directions
    k_scatter<<<(E_PIN * 8) / 256, 256, 0, stream>>>(
        cell_feat, net_feat, pins_src, pins_dst,
        net_sum, net_maxk, net_cnt, cell_sum, cell_maxk, cell_cnt);

    // Stage B: node MLPs
    k_node24<<<(N_CELL + 3) / 4, 256, 0, stream>>>(
        cell_feat, cell_sum, cell_maxk, cell_cnt, W_cell, b_cell, hc, N_CELL);
    k_node24<<<(N_NET + 3) / 4, 256, 0, stream>>>(
        net_feat, net_sum, net_maxk, net_cnt, W_net, b_net, hn, N_NET);

    // Stage C: edge weights (pre-divided by dst-cell count)
    k_ew<<<(E_PIN + 255) / 256, 256, 0, stream>>>(
        pin_feat, W_pin, b_pin, W_ew, b_ew, pins_src, cell_cnt, ew);

    // hnW = hn @ W_neigh  (overlays freed stage-A scratch)
    k_hnw<<<(N_NET + 3) / 4, 256, 0, stream>>>(hn, W_neigh, hnW, N_NET);

    // hidden := hc @ W_self + b_sage (in place)
    k_self<<<(N_CELL + 3) / 4, 256, 0, stream>>>(hc, W_self, b_sage, N_CELL);

    // Stage D: hidden[src] += hnW[dst] * ew
    k_msg<<<(E_PIN * 64) / 256, 256, 0, stream>>>(hnW, ew, pins_src, pins_dst, hc);

    // Stage E: edge readouts
    k_edge<<<(E2 + 3) / 4, 256, 0, stream>>>(
        hc, hn, fathers, sons, grandf, fs_nets, gf_nets,
        W_dis, b_dis, W_def, b_def, cell_size, (float*)d_out);
}